// Round 6
// baseline (633.568 us; speedup 1.0000x reference)
//
#include <hip/hip_runtime.h>

#define NUM_K 1024
#define DIM 256
#define HW 4096
#define CHW (DIM * HW)
#define LOSSOFF 16777216
#define IDXOFF 16777217
#define BN 64
#define BK 64
#define DC 64

// fl(x*x), opaque to the optimizer so it can never be contracted into an FMA
// (numpy materializes flat*flat before pairwise-summing it: products are
// rounded separately, sums are plain fp32 adds).
__device__ __forceinline__ float sqnc(float v) {
    float p = v * v;
    asm volatile("" : "+v"(p));
    return p;
}

// numpy pairwise_sum of fl(x_d^2) over d=0..255 (contiguous-axis algorithm):
// n=256 -> split 128+128; each 128-block: 8 accumulators r[j] += a[i+j],
// combined ((r0+r1)+(r2+r3))+((r4+r5)+(r6+r7)); result S0+S1.
// (Exact numpy SIMD order not critical: integer-ulp errors in A shift all
// scores of a row uniformly -> argmin-invariant; see round-5 analysis.)
__device__ __forceinline__ float np_sumsq256(const float* p, int stride) {
    float S[2];
#pragma unroll
    for (int h = 0; h < 2; ++h) {
        const float* a = p + h * 128 * stride;
        float r[8];
#pragma unroll
        for (int j = 0; j < 8; ++j) r[j] = sqnc(a[j * stride]);
        for (int i = 8; i < 128; i += 8) {
#pragma unroll
            for (int j = 0; j < 8; ++j) r[j] = r[j] + sqnc(a[(i + j) * stride]);
        }
        S[h] = ((r[0] + r[1]) + (r[2] + r[3])) + ((r[4] + r[5]) + (r[6] + r[7]));
    }
    return S[0] + S[1];
}

// ws layout (floats): [0]=loss accum, [16..16+1024) = B_k = np.sum(e_k^2) (numpy semantics)
__global__ __launch_bounds__(256) void vq_prep(const float* __restrict__ cb,
                                               float* __restrict__ wsf) {
    int k = blockIdx.x * blockDim.x + threadIdx.x;
    if (k == 0) wsf[0] = 0.0f;
    if (k < NUM_K) wsf[16 + k] = np_sumsq256(cb + (size_t)k * DIM, 1);
}

__global__ __launch_bounds__(256, 2) void vq_main(const float* __restrict__ in,
                                                  const float* __restrict__ cb,
                                                  float* __restrict__ wsf,
                                                  float* __restrict__ out) {
    // 64 KB X tile ([d][n], full D) + 16 KB codebook chunk ([d][k], XOR-swizzled)
    __shared__ float xs[DIM * BN];
    __shared__ float es[DC * BK];

    const int tid = threadIdx.x;
    const int tr = tid >> 4;   // row group 0..15 (4 rows each)
    const int tc = tid & 15;   // col group 0..15 (4 codes each)
    const int n0 = blockIdx.x * BN;
    const int gbase = (n0 >> 12) * CHW + (n0 & 4095);  // NCHW base for this tile
    const float* cn = wsf + 16;

    // ---- stage X once: in[gbase + d*HW + n], coalesced float4 over n ----
#pragma unroll
    for (int i = 0; i < 16; ++i) {
        int f = i * 256 + tid;
        int dl = f >> 4;      // 0..255
        int n4 = f & 15;      // float4 index within 64 n's
        *(float4*)(xs + dl * BN + n4 * 4) =
            *(const float4*)(in + gbase + dl * HW + n4 * 4);
    }

    // ---- prefetch codebook chunk 0 into registers ----
    float4 pf[4];
#pragma unroll
    for (int i = 0; i < 4; ++i) {
        int f = i * 256 + tid;
        int kk = f >> 4;   // code within tile 0..63
        int d4 = f & 15;   // float4 index within 64 d's
        pf[i] = *(const float4*)(cb + kk * DIM + d4 * 4);
    }

    // ---- A_n = np.sum(x_n^2) per row, numpy pairwise semantics ----
    __syncthreads();  // xs visible
    if (tid < BN) es[tid] = np_sumsq256(xs + tid, BN);  // es[0..63] scratch
    __syncthreads();
    float A_r[4];
#pragma unroll
    for (int i = 0; i < 4; ++i) A_r[i] = es[tr * 4 + i];
    // main loop's leading __syncthreads() protects es before first commit

    float b1[4];
    int i1[4];
#pragma unroll
    for (int i = 0; i < 4; ++i) { b1[i] = 3.0e38f; i1[i] = 0; }

    int q = 0;  // linear chunk id = kt*4 + dc
    for (int kt = 0; kt < NUM_K / BK; ++kt) {
        float acc[4][4];
#pragma unroll
        for (int i = 0; i < 4; ++i)
#pragma unroll
            for (int j = 0; j < 4; ++j) acc[i][j] = 0.0f;

        for (int dc = 0; dc < DIM / DC; ++dc, ++q) {
            __syncthreads();  // previous chunk's readers (and A_r reads) done
            // commit prefetched chunk to LDS, transposed to [d][k], XOR-swizzled cols
#pragma unroll
            for (int i = 0; i < 4; ++i) {
                int f = i * 256 + tid;
                int kk = f >> 4;
                int d4 = f & 15;
                int col = kk ^ ((d4 & 7) << 2);
                es[(d4 * 4 + 0) * BK + col] = pf[i].x;
                es[(d4 * 4 + 1) * BK + col] = pf[i].y;
                es[(d4 * 4 + 2) * BK + col] = pf[i].z;
                es[(d4 * 4 + 3) * BK + col] = pf[i].w;
            }
            __syncthreads();
            // prefetch next chunk (in flight across the FMA loop)
            {
                int qn = (q + 1) & 63;
                int ktn = qn >> 2, dcn = qn & 3;
#pragma unroll
                for (int i = 0; i < 4; ++i) {
                    int f = i * 256 + tid;
                    int kk = f >> 4;
                    int d4 = f & 15;
                    pf[i] = *(const float4*)(cb + (ktn * BK + kk) * DIM + dcn * DC + d4 * 4);
                }
            }
            // ---- dot accumulation: sequential-d fmaf chain (= BLAS sgemm
            //      microkernel semantics: one fp32 FMA accumulator per C
            //      element, k ascending, single pass since K=256 <= KC) ----
            const float* xb = xs + dc * DC * BN + tr * 4;
#pragma unroll 8
            for (int d = 0; d < DC; ++d) {
                float4 x4 = *(const float4*)(xb + d * BN);
                float4 e4 = *(const float4*)(es + d * BK + ((tc * 4) ^ (((d >> 2) & 7) << 2)));
                float xr[4] = {x4.x, x4.y, x4.z, x4.w};
                float er[4] = {e4.x, e4.y, e4.z, e4.w};
#pragma unroll
                for (int i = 0; i < 4; ++i)
#pragma unroll
                    for (int j = 0; j < 4; ++j)
                        acc[i][j] = fmaf(xr[i], er[j], acc[i][j]);
            }
        }
        // ---- epilogue: D = fl(fl(A+B) - fl(2*dot)), numpy expression order.
        //      acc+acc is exact; opacity barrier prevents re-fusing into fma.
#pragma unroll
        for (int j = 0; j < 4; ++j) {
            int k = kt * BK + tc * 4 + j;
            float Bk = cn[k];
#pragma unroll
            for (int i = 0; i < 4; ++i) {
                float AB = A_r[i] + Bk;
                float twoa = acc[i][j] + acc[i][j];
                asm volatile("" : "+v"(twoa));
                float s = AB - twoa;
                if (s < b1[i]) { b1[i] = s; i1[i] = k; }  // strict <: first index kept
            }
        }
    }

    // ---- reduce (min, argmin) across the 16 tc lanes sharing each row;
    //      ties (now real fp32 ties) break to the smaller index ----
#pragma unroll
    for (int m = 1; m < 16; m <<= 1) {
#pragma unroll
        for (int i = 0; i < 4; ++i) {
            float so = __shfl_xor(b1[i], m);
            int io = __shfl_xor(i1[i], m);
            if (so < b1[i] || (so == b1[i] && io < i1[i])) {
                b1[i] = so;
                i1[i] = io;
            }
        }
    }

    __syncthreads();  // all es readers done before overlaying
    int* kmin_s = (int*)es;      // overlay on es (no longer needed)
    float* lred = es + 64;
    if (tc == 0) {
#pragma unroll
        for (int i = 0; i < 4; ++i) kmin_s[tr * 4 + i] = i1[i];
    }
    __syncthreads();

    // indices output (as float)
    if (tid < BN) out[IDXOFF + n0 + tid] = (float)kmin_s[tid];

    // quantized output (coalesced over n per d) + fused loss partial
    const int n = tid & 63;
    const int d0 = (tid >> 6) * 64;
    const int kmin = kmin_s[n];
    const float4* crow = (const float4*)(cb + kmin * DIM + d0);
    float lsum = 0.0f;
#pragma unroll 4
    for (int dj = 0; dj < 16; ++dj) {
        float4 q4 = crow[dj];
#pragma unroll
        for (int l = 0; l < 4; ++l) {
            int d = d0 + dj * 4 + l;
            float qv = ((const float*)&q4)[l];
            float xv = xs[d * BN + n];
            out[gbase + d * HW + n] = qv;
            float df = qv - xv;
            lsum = fmaf(df, df, lsum);
        }
    }
#pragma unroll
    for (int m = 1; m < 64; m <<= 1) lsum += __shfl_xor(lsum, m);
    if ((tid & 63) == 0) lred[tid >> 6] = lsum;
    __syncthreads();
    if (tid == 0) atomicAdd(wsf, lred[0] + lred[1] + lred[2] + lred[3]);
}

__global__ void vq_finish(const float* __restrict__ wsf, float* __restrict__ out) {
    out[LOSSOFF] = wsf[0] * (1.25f / 16777216.0f);
}

extern "C" void kernel_launch(void* const* d_in, const int* in_sizes, int n_in,
                              void* d_out, int out_size, void* d_ws, size_t ws_size,
                              hipStream_t stream) {
    const float* in = (const float*)d_in[0];
    const float* cb = (const float*)d_in[1];
    float* out = (float*)d_out;
    float* wsf = (float*)d_ws;

    vq_prep<<<4, 256, 0, stream>>>(cb, wsf);
    vq_main<<<1024, 256, 0, stream>>>(in, cb, wsf, out);
    vq_finish<<<1, 1, 0, stream>>>(wsf, out);
}